// Round 17
// baseline (185.859 us; speedup 1.0000x reference)
//
#include <hip/hip_runtime.h>
#include <hip/hip_bf16.h>

#define B_N 32
#define SX 2048
#define SY 512
#define DIM 1024
#define NTOK 2
#define DN 128
#define ODIM 1024
#define BM 64      // rows per panel
#define BK 64
#define NT 16      // K tiles per panel

typedef __bf16 bf16;
typedef __bf16 bf16x8 __attribute__((ext_vector_type(8)));
typedef __bf16 bf16x4 __attribute__((ext_vector_type(4)));
typedef float f32x4 __attribute__((ext_vector_type(4)));

typedef __attribute__((address_space(3))) unsigned char lds_u8;
typedef const __attribute__((address_space(1))) unsigned char glb_u8;

__device__ __forceinline__ f32x4 mfma16(bf16x8 a, bf16x8 b, f32x4 c) {
  return __builtin_amdgcn_mfma_f32_16x16x32_bf16(a, b, c, 0, 0, 0);
}
__device__ __forceinline__ void gll16(const void* g, void* l) {
  __builtin_amdgcn_global_load_lds((glb_u8*)g, (lds_u8*)l, 16, 0, 0);
}
__device__ __forceinline__ void waitv(int n) {
  switch (n) {
    case 0: asm volatile("s_waitcnt vmcnt(0)" ::: "memory"); break;
    case 4: asm volatile("s_waitcnt vmcnt(4)" ::: "memory"); break;
    case 8: asm volatile("s_waitcnt vmcnt(8)" ::: "memory"); break;
    case 12: asm volatile("s_waitcnt vmcnt(12)" ::: "memory"); break;
    case 16: asm volatile("s_waitcnt vmcnt(16)" ::: "memory"); break;
    default: asm volatile("s_waitcnt vmcnt(20)" ::: "memory"); break;
  }
}

// Convert weights fp32 -> bf16 once per call.
__global__ __launch_bounds__(256) void prep_kernel(const float* __restrict__ Wd,
                                                   const float* __restrict__ Wu,
                                                   bf16* __restrict__ wdb,
                                                   bf16* __restrict__ wub) {
  int i = blockIdx.x * 256 + threadIdx.x;
  if (i < DN * DIM) {
    wdb[i] = (bf16)Wd[i];
    wub[i] = (bf16)Wu[i];
  }
}

// tokens kernel: only needed when gate != 0 (bench has gate == 0).
__global__ __launch_bounds__(256) void tokens_kernel(const float* __restrict__ y,
                                                     const float* __restrict__ lat,
                                                     const float* __restrict__ gate,
                                                     float* __restrict__ tokens) {
  if (gate[0] == 0.0f) return;
  __shared__ float s_lat[NTOK][DIM];
  __shared__ float s_sc[NTOK][SY];
  int b = blockIdx.x;
  int tid = threadIdx.x, wave = tid >> 6, lane = tid & 63;
  const float* yb = y + (size_t)b * SY * DIM;
  for (int i = tid; i < NTOK * DIM; i += 256) ((float*)s_lat)[i] = lat[i];
  __syncthreads();
  for (int s = wave * 128; s < wave * 128 + 128; ++s) {
    const float* yr = yb + (size_t)s * DIM;
    float d0 = 0.f, d1 = 0.f;
#pragma unroll
    for (int i = 0; i < 4; ++i) {
      f32x4 v = *(const f32x4*)(yr + lane * 4 + i * 256);
      f32x4 l0 = *(const f32x4*)(&s_lat[0][lane * 4 + i * 256]);
      f32x4 l1 = *(const f32x4*)(&s_lat[1][lane * 4 + i * 256]);
      d0 += v[0] * l0[0] + v[1] * l0[1] + v[2] * l0[2] + v[3] * l0[3];
      d1 += v[0] * l1[0] + v[1] * l1[1] + v[2] * l1[2] + v[3] * l1[3];
    }
#pragma unroll
    for (int off = 32; off > 0; off >>= 1) {
      d0 += __shfl_xor(d0, off);
      d1 += __shfl_xor(d1, off);
    }
    if (lane == 0) { s_sc[0][s] = d0; s_sc[1][s] = d1; }
  }
  __syncthreads();
  if (wave < 2) {
    float m = -3.4e38f;
    for (int s = lane; s < SY; s += 64) m = fmaxf(m, s_sc[wave][s]);
#pragma unroll
    for (int off = 32; off > 0; off >>= 1) m = fmaxf(m, __shfl_xor(m, off));
    float sum = 0.f;
    for (int s = lane; s < SY; s += 64) {
      float e = expf(s_sc[wave][s] - m);
      s_sc[wave][s] = e;
      sum += e;
    }
#pragma unroll
    for (int off = 32; off > 0; off >>= 1) sum += __shfl_xor(sum, off);
    float inv = 1.f / sum;
    for (int s = lane; s < SY; s += 64) s_sc[wave][s] *= inv;
  }
  __syncthreads();
  float a0[4] = {0.f, 0.f, 0.f, 0.f}, a1[4] = {0.f, 0.f, 0.f, 0.f};
  for (int s = 0; s < SY; ++s) {
    float p0 = s_sc[0][s], p1 = s_sc[1][s];
    const float* yr = yb + (size_t)s * DIM;
#pragma unroll
    for (int i = 0; i < 4; ++i) {
      float v = yr[tid + i * 256];
      a0[i] += p0 * v;
      a1[i] += p1 * v;
    }
  }
  float* tb = tokens + (size_t)b * NTOK * DIM;
#pragma unroll
  for (int i = 0; i < 4; ++i) {
    tb[tid + i * 256] = s_lat[0][tid + i * 256] + a0[i];
    tb[DIM + tid + i * 256] = s_lat[1][tid + i * 256] + a1[i];
  }
}

// gate != 0 slow path only: xp = x + softmax(x.tok)*tok*gate, into d_out.
__global__ __launch_bounds__(256) void xprime_kernel(const float* __restrict__ x,
                                                     const float* __restrict__ gate,
                                                     const float* __restrict__ tokens,
                                                     float* __restrict__ xp) {
  float g = gate[0];
  if (g == 0.0f) return;
  __shared__ float s_tok[NTOK][DIM];
  __shared__ float s_c[BM][2];
  int tid = threadIdx.x, w = tid >> 6, lane = tid & 63;
  size_t m0 = (size_t)blockIdx.x * BM;
  int b = (int)(m0 / SX);
  const float* xb = x + m0 * DIM;
  const float* tokb = tokens + (size_t)b * NTOK * DIM;
  for (int i = tid; i < NTOK * DIM; i += 256) ((float*)s_tok)[i] = tokb[i];
  __syncthreads();
  for (int i = 0; i < 16; ++i) {
    int r = w * 16 + i;
    const float* xrow = xb + (size_t)r * DIM;
    float d0 = 0.f, d1 = 0.f;
#pragma unroll
    for (int c = 0; c < 4; ++c) {
      f32x4 v = *(const f32x4*)(xrow + lane * 4 + c * 256);
      f32x4 t0 = *(const f32x4*)(&s_tok[0][lane * 4 + c * 256]);
      f32x4 t1 = *(const f32x4*)(&s_tok[1][lane * 4 + c * 256]);
      d0 += v[0] * t0[0] + v[1] * t0[1] + v[2] * t0[2] + v[3] * t0[3];
      d1 += v[0] * t1[0] + v[1] * t1[1] + v[2] * t1[2] + v[3] * t1[3];
    }
#pragma unroll
    for (int off = 32; off > 0; off >>= 1) {
      d0 += __shfl_xor(d0, off);
      d1 += __shfl_xor(d1, off);
    }
    if (lane == 0) {
      float mm = fmaxf(d0, d1);
      float e0 = expf(d0 - mm), e1 = expf(d1 - mm);
      float inv = g / (e0 + e1);
      s_c[r][0] = e0 * inv;
      s_c[r][1] = e1 * inv;
    }
  }
  __syncthreads();
  float* xpb = xp + m0 * DIM;
  for (int r = w * 16; r < w * 16 + 16; ++r) {
    float c0 = s_c[r][0], c1 = s_c[r][1];
#pragma unroll
    for (int c = 0; c < 4; ++c) {
      f32x4 v = *(const f32x4*)(xb + (size_t)r * DIM + lane * 4 + c * 256);
      f32x4 t0 = *(const f32x4*)(&s_tok[0][lane * 4 + c * 256]);
      f32x4 t1 = *(const f32x4*)(&s_tok[1][lane * 4 + c * 256]);
      f32x4 o;
#pragma unroll
      for (int j = 0; j < 4; ++j) o[j] = v[j] + c0 * t0[j] + c1 * t1[j];
      *(f32x4*)(xpb + (size_t)r * DIM + lane * 4 + c * 256) = o;
    }
  }
}

// 2-panel fused kernel, R12 schedule + line-complete EPI interleave.
// Block = 128 rows (2 x 64-row panels), grid 512. Panel-0 K-loop = R12.
// Panel-0's GEMM2 runs as 4 PAIRED strips (32 cols = full 128B line/row)
// interleaved one pair per 4 tiles of panel-1's K-loop. Z0 kept in a second
// 16KB LDS buffer, re-read per EPI via ds_read (lgkm only). Wu preloaded to
// 128 VGPR (in-loop wu VMEM loads would force vmcnt(0) drains). Panel-1
// vmcnt immediates account for the 8 stores/pair in the FIFO.
__global__ __launch_bounds__(512) void main_kernel(const float* __restrict__ x,
                                                   const float* __restrict__ gate,
                                                   const float* __restrict__ xp,
                                                   const bf16* __restrict__ wdb,
                                                   const bf16* __restrict__ wub,
                                                   float* __restrict__ out) {
  // [0,65536): x ring (4 x 16KB fp32 64x64)
  // [65536,131072): wd ring (4 x 16KB bf16 128x64)
  // [131072,147456): Z0 (panel-0), [147456,163840): Z1 (panel-1)
  __shared__ __align__(16) char smem[163840];

  int tid = threadIdx.x, w = tid >> 6, l = tid & 63;
  int lq = l >> 4, lr = l & 15;
  int wr = w >> 2, wc = w & 3;  // 2 row-groups x 4 dn-groups
  size_t m0 = (size_t)blockIdx.x * (2 * BM);
  float g = gate[0];
  const float* xbA = ((g != 0.f) ? xp : x) + m0 * DIM;

  // ---- Wu preload: 8 strips x 4 kt for this wave's 128 out-cols ----
  bf16x8 wu[8][4];
#pragma unroll
  for (int s = 0; s < 8; ++s)
#pragma unroll
    for (int kt = 0; kt < 4; ++kt)
      wu[s][kt] = *(const bf16x8*)(wub + (size_t)(w * 128 + s * 16 + lr) * DN +
                                   kt * 32 + lq * 8);

  // ---- pre-swizzled gll source pointers (per lane), panel-0 base ----
  const char* xsrc[2];
  const char* wsrc[2];
#pragma unroll
  for (int j = 0; j < 2; ++j) {
    int xr = w * 8 + j * 4 + (l >> 4);
    int xcb = ((l & 15) * 16) ^ ((j * 4 + (l >> 4)) << 5);
    xsrc[j] = (const char*)xbA + (size_t)xr * (DIM * 4) + xcb;
    int wr_ = w * 16 + j * 8 + (l >> 3);
    int wcb = ((l & 7) * 16) ^ ((l >> 3) << 4);
    wsrc[j] = (const char*)wdb + (size_t)wr_ * (DIM * 2) + wcb;
  }
  const size_t POFF = (size_t)BM * DIM * 4;  // panel-1 byte offset in x

  f32x4 acc[2][2] = {};  // [mt][nf]

  auto STAGE = [&](int t, int panel) {
    int b = t & 3;
#pragma unroll
    for (int j = 0; j < 2; ++j)
      gll16(xsrc[j] + (size_t)panel * POFF + (size_t)t * (BK * 4),
            smem + b * 16384 + (w * 8 + j * 4) * 256);
#pragma unroll
    for (int j = 0; j < 2; ++j)
      gll16(wsrc[j] + (size_t)t * (BK * 2),
            smem + 65536 + b * 16384 + (w * 16 + j * 8) * 128);
  };

  auto COMP = [&](int b) {
    const char* xt = smem + b * 16384;
    const char* wt = smem + 65536 + b * 16384;
    __builtin_amdgcn_s_setprio(1);
#pragma unroll
    for (int kc = 0; kc < 2; ++kc) {
      bf16x8 wdf[2];
#pragma unroll
      for (int nf = 0; nf < 2; ++nf) {
        int dn = wc * 32 + nf * 16 + lr;
        wdf[nf] = *(const bf16x8*)(wt + dn * 128 +
                                   ((kc * 64 + lq * 16) ^ ((lr & 7) << 4)));
      }
#pragma unroll
      for (int mt = 0; mt < 2; ++mt) {
        int row = wr * 32 + mt * 16 + lr;
        int sz = (row & 7) << 5;
        int kb = kc * 128 + lq * 32;
        f32x4 a0 = *(const f32x4*)(xt + row * 256 + (kb ^ sz));
        f32x4 a1 = *(const f32x4*)(xt + row * 256 + ((kb + 16) ^ sz));
        bf16x8 xf;
#pragma unroll
        for (int jj = 0; jj < 4; ++jj) {
          xf[jj] = (bf16)a0[jj];
          xf[4 + jj] = (bf16)a1[jj];
        }
        acc[mt][0] = mfma16(wdf[0], xf, acc[mt][0]);
        acc[mt][1] = mfma16(wdf[1], xf, acc[mt][1]);
      }
    }
    __builtin_amdgcn_s_setprio(0);
  };

  auto ZWRITE = [&](int zoff) {
    char* zls = smem + zoff;
#pragma unroll
    for (int mt = 0; mt < 2; ++mt)
#pragma unroll
      for (int nf = 0; nf < 2; ++nf) {
        int xr = wr * 32 + mt * 16 + lr;
        int dn = wc * 32 + nf * 16 + lq * 4;
        bf16x4 pk;
#pragma unroll
        for (int r = 0; r < 4; ++r) pk[r] = (bf16)fmaxf(acc[mt][nf][r], 0.f);
        *(bf16x4*)(zls + xr * (DN * 2) + ((dn * 2) ^ ((xr & 7) << 4))) = pk;
      }
  };

  // EPI pair p: strips 2p,2p+1 -> cols [w*128+32p, +32) = one 128B line/row.
  // zF from LDS (ds_read, lgkm only), wu from preloaded regs -> the only
  // vmcnt ops added are the 8 stores.
  auto EPIpair = [&](int p, const char* zbase, float* ob) {
    bf16x8 zF[4][4];
#pragma unroll
    for (int mt = 0; mt < 4; ++mt)
#pragma unroll
      for (int kt = 0; kt < 4; ++kt) {
        int xr = mt * 16 + lr;
        zF[kt][mt] = *(const bf16x8*)(zbase + xr * (DN * 2) +
                                      (((kt * 32 + lq * 8) * 2) ^ ((xr & 7) << 4)));
      }
#pragma unroll
    for (int s2 = 0; s2 < 2; ++s2) {
      int s = 2 * p + s2;
      f32x4 a2[4] = {};
#pragma unroll
      for (int kt = 0; kt < 4; ++kt)
#pragma unroll
        for (int mt = 0; mt < 4; ++mt)
          a2[mt] = mfma16(wu[s][kt], zF[kt][mt], a2[mt]);
#pragma unroll
      for (int mt = 0; mt < 4; ++mt)
        *(f32x4*)(ob + (size_t)(mt * 16 + lr) * ODIM + w * 128 + s * 16 + lq * 4) = a2[mt];
    }
  };

  // ================= panel 0 K-loop (pure R12 schedule) =================
  STAGE(0, 0); STAGE(1, 0); STAGE(2, 0); STAGE(3, 0);
#pragma unroll
  for (int t = 0; t < NT; ++t) {
    waitv(t <= NT - 4 ? 12 : (t == NT - 3 ? 8 : (t == NT - 2 ? 4 : 0)));
    __builtin_amdgcn_sched_barrier(0);
    __builtin_amdgcn_s_barrier();
    COMP(t & 3);
    __builtin_amdgcn_sched_barrier(0);
    __builtin_amdgcn_s_barrier();
    if (t + 4 < NT) STAGE(t + 4, 0);
  }

  // ====== inter-panel: prologue panel-1 FIRST, then Z0 exchange ======
  STAGE(0, 1); STAGE(1, 1); STAGE(2, 1); STAGE(3, 1);
  ZWRITE(131072);
  asm volatile("s_waitcnt lgkmcnt(0)" ::: "memory");
  __builtin_amdgcn_sched_barrier(0);
  __builtin_amdgcn_s_barrier();
#pragma unroll
  for (int mt = 0; mt < 2; ++mt)
#pragma unroll
    for (int nf = 0; nf < 2; ++nf) acc[mt][nf] = (f32x4){0.f, 0.f, 0.f, 0.f};

  // ========== panel 1 K-loop with paired panel-0 epilogue ==========
  // FIFO accounting (4 gll/STAGE, 8 stores/pair, in-order retirement):
  // t=0:12 ; t=1..12:20 ; t=13:16 ; t=14:12 ; t=15:8.
  float* obA = out + m0 * ODIM;
  const char* z0 = smem + 131072;
  constexpr int WB[16] = {12, 20, 20, 20, 20, 20, 20, 20,
                          20, 20, 20, 20, 20, 16, 12, 8};
#pragma unroll
  for (int t = 0; t < NT; ++t) {
    waitv(WB[t]);
    __builtin_amdgcn_sched_barrier(0);
    __builtin_amdgcn_s_barrier();
    COMP(t & 3);
    __builtin_amdgcn_sched_barrier(0);
    __builtin_amdgcn_s_barrier();
    if (t + 4 < NT) STAGE(t + 4, 1);
    if ((t & 3) == 0) EPIpair(t >> 2, z0, obA);  // line-complete 32-col pair
  }

  // ================= panel 1 epilogue (back-to-back pairs) =================
  ZWRITE(147456);
  asm volatile("s_waitcnt lgkmcnt(0)" ::: "memory");
  __builtin_amdgcn_sched_barrier(0);
  __builtin_amdgcn_s_barrier();
  float* obB = out + (m0 + BM) * ODIM;
  const char* z1 = smem + 147456;
#pragma unroll
  for (int p = 0; p < 4; ++p) EPIpair(p, z1, obB);
}

extern "C" void kernel_launch(void* const* d_in, const int* in_sizes, int n_in,
                              void* d_out, int out_size, void* d_ws, size_t ws_size,
                              hipStream_t stream) {
  const float* x = (const float*)d_in[0];
  const float* y = (const float*)d_in[1];
  const float* lat = (const float*)d_in[2];
  const float* gate = (const float*)d_in[3];
  const float* Wd = (const float*)d_in[4];
  const float* Wu = (const float*)d_in[5];
  float* out = (float*)d_out;
  char* ws = (char*)d_ws;

  float* tokens = (float*)ws;              // 262144 B
  bf16* wdb = (bf16*)(ws + 262144);        // 262144 B
  bf16* wub = (bf16*)(ws + 524288);        // 262144 B

  prep_kernel<<<(DN * DIM + 255) / 256, 256, 0, stream>>>(Wd, Wu, wdb, wub);
  tokens_kernel<<<B_N, 256, 0, stream>>>(y, lat, gate, tokens);
  // gate!=0 only: writes x' into d_out; main reads each panel's rows fully
  // before overwriting them (EPI-pair stores hit only panel-0 rows, disjoint
  // from panel-1's x' staging reads).
  xprime_kernel<<<(B_N * SX) / BM, 256, 0, stream>>>(x, gate, tokens, out);
  main_kernel<<<(B_N * SX) / (2 * BM), 512, 0, stream>>>(x, gate, out, wdb, wub, out);
}

// Round 18
// 144.673 us; speedup vs baseline: 1.2847x; 1.2847x over previous
//
#include <hip/hip_runtime.h>
#include <hip/hip_bf16.h>

#define B_N 32
#define SX 2048
#define SY 512
#define DIM 1024
#define NTOK 2
#define DN 128
#define ODIM 1024
#define BM 64
#define BK 64
#define NT 16   // K tiles
#define RING 4

typedef __bf16 bf16;
typedef __bf16 bf16x8 __attribute__((ext_vector_type(8)));
typedef __bf16 bf16x4 __attribute__((ext_vector_type(4)));
typedef float f32x4 __attribute__((ext_vector_type(4)));

typedef __attribute__((address_space(3))) unsigned char lds_u8;
typedef const __attribute__((address_space(1))) unsigned char glb_u8;

__device__ __forceinline__ f32x4 mfma16(bf16x8 a, bf16x8 b, f32x4 c) {
  return __builtin_amdgcn_mfma_f32_16x16x32_bf16(a, b, c, 0, 0, 0);
}
__device__ __forceinline__ void gll16(const void* g, void* l) {
  __builtin_amdgcn_global_load_lds((glb_u8*)g, (lds_u8*)l, 16, 0, 0);
}

// Convert weights fp32 -> bf16 once per call.
__global__ __launch_bounds__(256) void prep_kernel(const float* __restrict__ Wd,
                                                   const float* __restrict__ Wu,
                                                   bf16* __restrict__ wdb,
                                                   bf16* __restrict__ wub) {
  int i = blockIdx.x * 256 + threadIdx.x;
  if (i < DN * DIM) {
    wdb[i] = (bf16)Wd[i];
    wub[i] = (bf16)Wu[i];
  }
}

// tokens kernel: only needed when gate != 0 (bench has gate == 0).
__global__ __launch_bounds__(256) void tokens_kernel(const float* __restrict__ y,
                                                     const float* __restrict__ lat,
                                                     const float* __restrict__ gate,
                                                     float* __restrict__ tokens) {
  if (gate[0] == 0.0f) return;
  __shared__ float s_lat[NTOK][DIM];
  __shared__ float s_sc[NTOK][SY];
  int b = blockIdx.x;
  int tid = threadIdx.x, wave = tid >> 6, lane = tid & 63;
  const float* yb = y + (size_t)b * SY * DIM;
  for (int i = tid; i < NTOK * DIM; i += 256) ((float*)s_lat)[i] = lat[i];
  __syncthreads();
  for (int s = wave * 128; s < wave * 128 + 128; ++s) {
    const float* yr = yb + (size_t)s * DIM;
    float d0 = 0.f, d1 = 0.f;
#pragma unroll
    for (int i = 0; i < 4; ++i) {
      f32x4 v = *(const f32x4*)(yr + lane * 4 + i * 256);
      f32x4 l0 = *(const f32x4*)(&s_lat[0][lane * 4 + i * 256]);
      f32x4 l1 = *(const f32x4*)(&s_lat[1][lane * 4 + i * 256]);
      d0 += v[0] * l0[0] + v[1] * l0[1] + v[2] * l0[2] + v[3] * l0[3];
      d1 += v[0] * l1[0] + v[1] * l1[1] + v[2] * l1[2] + v[3] * l1[3];
    }
#pragma unroll
    for (int off = 32; off > 0; off >>= 1) {
      d0 += __shfl_xor(d0, off);
      d1 += __shfl_xor(d1, off);
    }
    if (lane == 0) { s_sc[0][s] = d0; s_sc[1][s] = d1; }
  }
  __syncthreads();
  if (wave < 2) {
    float m = -3.4e38f;
    for (int s = lane; s < SY; s += 64) m = fmaxf(m, s_sc[wave][s]);
#pragma unroll
    for (int off = 32; off > 0; off >>= 1) m = fmaxf(m, __shfl_xor(m, off));
    float sum = 0.f;
    for (int s = lane; s < SY; s += 64) {
      float e = expf(s_sc[wave][s] - m);
      s_sc[wave][s] = e;
      sum += e;
    }
#pragma unroll
    for (int off = 32; off > 0; off >>= 1) sum += __shfl_xor(sum, off);
    float inv = 1.f / sum;
    for (int s = lane; s < SY; s += 64) s_sc[wave][s] *= inv;
  }
  __syncthreads();
  float a0[4] = {0.f, 0.f, 0.f, 0.f}, a1[4] = {0.f, 0.f, 0.f, 0.f};
  for (int s = 0; s < SY; ++s) {
    float p0 = s_sc[0][s], p1 = s_sc[1][s];
    const float* yr = yb + (size_t)s * DIM;
#pragma unroll
    for (int i = 0; i < 4; ++i) {
      float v = yr[tid + i * 256];
      a0[i] += p0 * v;
      a1[i] += p1 * v;
    }
  }
  float* tb = tokens + (size_t)b * NTOK * DIM;
#pragma unroll
  for (int i = 0; i < 4; ++i) {
    tb[tid + i * 256] = s_lat[0][tid + i * 256] + a0[i];
    tb[DIM + tid + i * 256] = s_lat[1][tid + i * 256] + a1[i];
  }
}

// gate != 0 slow path only: xp = x + softmax(x.tok)*tok*gate, into d_out.
__global__ __launch_bounds__(256) void xprime_kernel(const float* __restrict__ x,
                                                     const float* __restrict__ gate,
                                                     const float* __restrict__ tokens,
                                                     float* __restrict__ xp) {
  float g = gate[0];
  if (g == 0.0f) return;
  __shared__ float s_tok[NTOK][DIM];
  __shared__ float s_c[BM][2];
  int tid = threadIdx.x, w = tid >> 6, lane = tid & 63;
  size_t m0 = (size_t)blockIdx.x * BM;
  int b = (int)(m0 / SX);
  const float* xb = x + m0 * DIM;
  const float* tokb = tokens + (size_t)b * NTOK * DIM;
  for (int i = tid; i < NTOK * DIM; i += 256) ((float*)s_tok)[i] = tokb[i];
  __syncthreads();
  for (int i = 0; i < 16; ++i) {
    int r = w * 16 + i;
    const float* xrow = xb + (size_t)r * DIM;
    float d0 = 0.f, d1 = 0.f;
#pragma unroll
    for (int c = 0; c < 4; ++c) {
      f32x4 v = *(const f32x4*)(xrow + lane * 4 + c * 256);
      f32x4 t0 = *(const f32x4*)(&s_tok[0][lane * 4 + c * 256]);
      f32x4 t1 = *(const f32x4*)(&s_tok[1][lane * 4 + c * 256]);
      d0 += v[0] * t0[0] + v[1] * t0[1] + v[2] * t0[2] + v[3] * t0[3];
      d1 += v[0] * t1[0] + v[1] * t1[1] + v[2] * t1[2] + v[3] * t1[3];
    }
#pragma unroll
    for (int off = 32; off > 0; off >>= 1) {
      d0 += __shfl_xor(d0, off);
      d1 += __shfl_xor(d1, off);
    }
    if (lane == 0) {
      float mm = fmaxf(d0, d1);
      float e0 = expf(d0 - mm), e1 = expf(d1 - mm);
      float inv = g / (e0 + e1);
      s_c[r][0] = e0 * inv;
      s_c[r][1] = e1 * inv;
    }
  }
  __syncthreads();
  float* xpb = xp + m0 * DIM;
  for (int r = w * 16; r < w * 16 + 16; ++r) {
    float c0 = s_c[r][0], c1 = s_c[r][1];
#pragma unroll
    for (int c = 0; c < 4; ++c) {
      f32x4 v = *(const f32x4*)(xb + (size_t)r * DIM + lane * 4 + c * 256);
      f32x4 t0 = *(const f32x4*)(&s_tok[0][lane * 4 + c * 256]);
      f32x4 t1 = *(const f32x4*)(&s_tok[1][lane * 4 + c * 256]);
      f32x4 o;
#pragma unroll
      for (int j = 0; j < 4; ++j) o[j] = v[j] + c0 * t0[j] + c1 * t1[j];
      *(f32x4*)(xpb + (size_t)r * DIM + lane * 4 + c * 256) = o;
    }
  }
}

// Fused bottleneck: gll ring-4 + counted vmcnt(12) => 12KB/wave (96KB/CU)
// reads in flight across barriers. 2x4 wave grid (32 rows x 32 dn per wave).
// 144KB LDS, 1 block/CU. (R18: verbatim revert to best-verified R12/R16
// configuration, 144.8 us — the session optimum.)
__global__ __launch_bounds__(512) void main_kernel(const float* __restrict__ x,
                                                   const float* __restrict__ gate,
                                                   const float* __restrict__ xp,
                                                   const bf16* __restrict__ wdb,
                                                   const bf16* __restrict__ wub,
                                                   float* __restrict__ out) {
  // [0,65536): x ring (4 x 16KB fp32 64x64)
  // [65536,131072): wd ring (4 x 16KB bf16 128x64)
  // [131072,147456): Z tile (bf16 64x128)
  __shared__ __align__(16) char smem[147456];

  int tid = threadIdx.x, w = tid >> 6, l = tid & 63;
  int lq = l >> 4, lr = l & 15;
  int wr = w >> 2, wc = w & 3;  // 2 row-groups x 4 dn-groups
  size_t m0 = (size_t)blockIdx.x * BM;
  float g = gate[0];
  const float* xb = ((g != 0.f) ? xp : x) + m0 * DIM;

  // ---- pre-swizzled gll source pointers (per lane) ----
  const char* xsrc[2];
  const char* wsrc[2];
#pragma unroll
  for (int j = 0; j < 2; ++j) {
    int xr = w * 8 + j * 4 + (l >> 4);                      // x row staged
    int xcb = ((l & 15) * 16) ^ ((j * 4 + (l >> 4)) << 5);  // pre-swizzled byte
    xsrc[j] = (const char*)xb + (size_t)xr * (DIM * 4) + xcb;
    int wr_ = w * 16 + j * 8 + (l >> 3);                    // wd row staged
    int wcb = ((l & 7) * 16) ^ ((l >> 3) << 4);
    wsrc[j] = (const char*)wdb + (size_t)wr_ * (DIM * 2) + wcb;
  }

  f32x4 acc[2][2] = {};  // [mt][nf]

  auto STAGE = [&](int t) {
    int b = t & 3;
#pragma unroll
    for (int j = 0; j < 2; ++j)
      gll16(xsrc[j] + (size_t)t * (BK * 4),
            smem + b * 16384 + (w * 8 + j * 4) * 256);
#pragma unroll
    for (int j = 0; j < 2; ++j)
      gll16(wsrc[j] + (size_t)t * (BK * 2),
            smem + 65536 + b * 16384 + (w * 16 + j * 8) * 128);
  };

  auto COMP = [&](int b) {
    const char* xt = smem + b * 16384;
    const char* wt = smem + 65536 + b * 16384;
    __builtin_amdgcn_s_setprio(1);
#pragma unroll
    for (int kc = 0; kc < 2; ++kc) {
      bf16x8 wdf[2];
#pragma unroll
      for (int nf = 0; nf < 2; ++nf) {
        int dn = wc * 32 + nf * 16 + lr;
        wdf[nf] = *(const bf16x8*)(wt + dn * 128 +
                                   ((kc * 64 + lq * 16) ^ ((lr & 7) << 4)));
      }
#pragma unroll
      for (int mt = 0; mt < 2; ++mt) {
        int row = wr * 32 + mt * 16 + lr;
        int sz = (row & 7) << 5;
        int kb = kc * 128 + lq * 32;
        f32x4 a0 = *(const f32x4*)(xt + row * 256 + (kb ^ sz));
        f32x4 a1 = *(const f32x4*)(xt + row * 256 + ((kb + 16) ^ sz));
        bf16x8 xf;
#pragma unroll
        for (int jj = 0; jj < 4; ++jj) {
          xf[jj] = (bf16)a0[jj];
          xf[4 + jj] = (bf16)a1[jj];
        }
        acc[mt][0] = mfma16(wdf[0], xf, acc[mt][0]);  // D[dn][xrow]
        acc[mt][1] = mfma16(wdf[1], xf, acc[mt][1]);
      }
    }
    __builtin_amdgcn_s_setprio(0);
  };

  // ---- prologue: fill the ring ----
  STAGE(0);
  STAGE(1);
  STAGE(2);
  STAGE(3);

#pragma unroll
  for (int t = 0; t < NT; ++t) {
    if (t <= NT - 4) {
      asm volatile("s_waitcnt vmcnt(12)" ::: "memory");  // tile t landed
    } else if (t == NT - 3) {
      asm volatile("s_waitcnt vmcnt(8)" ::: "memory");
    } else if (t == NT - 2) {
      asm volatile("s_waitcnt vmcnt(4)" ::: "memory");
    } else {
      asm volatile("s_waitcnt vmcnt(0)" ::: "memory");
    }
    __builtin_amdgcn_sched_barrier(0);
    __builtin_amdgcn_s_barrier();      // tile t in LDS for ALL waves
    COMP(t & 3);
    __builtin_amdgcn_sched_barrier(0); // pin reads before release barrier
    __builtin_amdgcn_s_barrier();      // all waves done reading tile t
    if (t + 4 < NT) STAGE(t + 4);      // refill the buffer just released
  }

  // ---- ReLU -> bf16 Z into swizzled LDS ----
  char* zls = smem + 131072;
#pragma unroll
  for (int mt = 0; mt < 2; ++mt)
#pragma unroll
    for (int nf = 0; nf < 2; ++nf) {
      int xr = wr * 32 + mt * 16 + lr;
      int dn = wc * 32 + nf * 16 + lq * 4;
      bf16x4 pk;
#pragma unroll
      for (int r = 0; r < 4; ++r) pk[r] = (bf16)fmaxf(acc[mt][nf][r], 0.f);
      *(bf16x4*)(zls + xr * (DN * 2) + ((dn * 2) ^ ((xr & 7) << 4))) = pk;
    }
  __syncthreads();

  // ---- GEMM2: out^T-frag = mfma(Wu, Z); packed f32x4 stores ----
  bf16x8 zF[4][4];  // [kt][mt]
#pragma unroll
  for (int mt = 0; mt < 4; ++mt)
#pragma unroll
    for (int kt = 0; kt < 4; ++kt) {
      int xr = mt * 16 + lr;
      zF[kt][mt] = *(const bf16x8*)(zls + xr * (DN * 2) +
                                    (((kt * 32 + lq * 8) * 2) ^ ((xr & 7) << 4)));
    }

  float* ob = out + m0 * ODIM;
#pragma unroll 2
  for (int oc16 = 0; oc16 < 8; ++oc16) {
    int base = w * 128 + oc16 * 16;  // wave w owns out cols [w*128, +128)
    bf16x8 wu[4];
#pragma unroll
    for (int kt = 0; kt < 4; ++kt)
      wu[kt] = *(const bf16x8*)(wub + (size_t)(base + lr) * DN + kt * 32 + lq * 8);
    f32x4 a2[4] = {};
#pragma unroll
    for (int kt = 0; kt < 4; ++kt)
#pragma unroll
      for (int mt = 0; mt < 4; ++mt)
        a2[mt] = mfma16(wu[kt], zF[kt][mt], a2[mt]);
#pragma unroll
    for (int mt = 0; mt < 4; ++mt)
      *(f32x4*)(ob + (size_t)(mt * 16 + lr) * ODIM + base + lq * 4) = a2[mt];
  }
}

extern "C" void kernel_launch(void* const* d_in, const int* in_sizes, int n_in,
                              void* d_out, int out_size, void* d_ws, size_t ws_size,
                              hipStream_t stream) {
  const float* x = (const float*)d_in[0];
  const float* y = (const float*)d_in[1];
  const float* lat = (const float*)d_in[2];
  const float* gate = (const float*)d_in[3];
  const float* Wd = (const float*)d_in[4];
  const float* Wu = (const float*)d_in[5];
  float* out = (float*)d_out;
  char* ws = (char*)d_ws;

  float* tokens = (float*)ws;              // 262144 B
  bf16* wdb = (bf16*)(ws + 262144);        // 262144 B
  bf16* wub = (bf16*)(ws + 524288);        // 262144 B

  prep_kernel<<<(DN * DIM + 255) / 256, 256, 0, stream>>>(Wd, Wu, wdb, wub);
  tokens_kernel<<<B_N, 256, 0, stream>>>(y, lat, gate, tokens);
  // gate!=0 only: writes x' into d_out; main reads it back per block before
  // overwriting that block's region with out.
  xprime_kernel<<<(B_N * SX) / BM, 256, 0, stream>>>(x, gate, tokens, out);
  main_kernel<<<(B_N * SX) / BM, 512, 0, stream>>>(x, gate, out, wdb, wub, out);
}